// Round 4
// baseline (364.817 us; speedup 1.0000x reference)
//
#include <hip/hip_runtime.h>

// Submanifold sparse 3D conv — v4: barrier-free, output-stationary-in-registers.
// Each wave owns 16 output rows, loops 27 items (26 reversed-map offsets + center).
// Hot loop per item: 1 table load (src row per column) -> 2x16B bf16 gather ->
// 8 W-frag loads (L1-hot) -> 8 MFMA into persistent f32x4 c[4]. No LDS, no
// barriers, no atomics, no converts.
//
// Prepasses (d_ws): feats f32->bf16 [N][64]; Wt [27][o][c] bf16; column table
// tab[26][nt][16] = omap or -1 (built from sorted imap by near-coalesced scatter).
//
// Map identity (verified R1/R2): out[imap[m,p]] += feats[omap[m,p]] @ kernel[26-kk(m)]

#define CIN 64
#define COUT 64
#define TROWS 16
#define NOFF 26

typedef short bf16x8 __attribute__((ext_vector_type(8)));
typedef float f32x4 __attribute__((ext_vector_type(4)));

__device__ inline unsigned short bfbits(float f) {
    unsigned u = __builtin_bit_cast(unsigned, f);
    u += 0x7fffu + ((u >> 16) & 1u);          // RNE
    return (unsigned short)(u >> 16);
}

__device__ inline int kk_of_item(int i) {
    return (i == 26) ? 13 : 26 - (i < 13 ? i : i + 1);
}

// ---------- prepass 1: feats f32 -> bf16 ----------------------------------
__global__ __launch_bounds__(256) void prep_feats(const float* __restrict__ f,
                                                  unsigned short* __restrict__ fb,
                                                  int n) {
    const int i8 = (blockIdx.x * 256 + threadIdx.x) * 8;
    if (i8 >= n) return;
    const float4 v0 = *(const float4*)(f + i8);
    const float4 v1 = *(const float4*)(f + i8 + 4);
    union { unsigned short u[8]; bf16x8 v; } r;
    r.u[0] = bfbits(v0.x); r.u[1] = bfbits(v0.y);
    r.u[2] = bfbits(v0.z); r.u[3] = bfbits(v0.w);
    r.u[4] = bfbits(v1.x); r.u[5] = bfbits(v1.y);
    r.u[6] = bfbits(v1.z); r.u[7] = bfbits(v1.w);
    *(bf16x8*)(fb + i8) = r.v;
}

// ---------- prepass 2: W [27][c][o] f32 -> Wt [27][o][c] bf16 -------------
__global__ __launch_bounds__(256) void prep_wt(const float* __restrict__ W,
                                               unsigned short* __restrict__ Wt) {
    const int k = blockIdx.x;
    for (int idx = threadIdx.x; idx < CIN * COUT; idx += 256) {
        const int c = idx >> 6, o = idx & 63;
        Wt[(k * 64 + o) * 64 + c] = bfbits(W[(k * 64 + c) * 64 + o]);
    }
}

// ---------- prepass 3: column table init (-1) + scatter -------------------
__global__ __launch_bounds__(256) void prep_tab_init(int4* __restrict__ tab4, int n4) {
    const int i = blockIdx.x * 256 + threadIdx.x;
    if (i < n4) tab4[i] = make_int4(-1, -1, -1, -1);
}

__global__ __launch_bounds__(256) void prep_tab(const int* __restrict__ imap,
                                                const int* __restrict__ omap,
                                                int P, int nt,
                                                int* __restrict__ tab) {
    const int p = blockIdx.x * 256 + threadIdx.x;
    const int m = blockIdx.y;
    if (p >= P) return;
    const int iv = imap[(size_t)m * P + p];
    if (iv < 0) return;                                    // -1 tail padding
    tab[((size_t)m * nt + (iv >> 4)) * 16 + (iv & 15)] = omap[(size_t)m * P + p];
}

// ---------- main ----------------------------------------------------------
__global__ __launch_bounds__(256) void spconv_v4(
    const unsigned short* __restrict__ fb,   // feats bf16 [N][64]
    const unsigned short* __restrict__ wt,   // [27][64][64] bf16 (o-major)
    const int* __restrict__ tab,             // [26][nt][16]
    float* __restrict__ out, int N, int nt)
{
    const int tid = threadIdx.x, w = tid >> 6, lane = tid & 63;
    const int col = lane & 15, grp = lane >> 4;
    const int t = blockIdx.x * 4 + w;
    if (t >= nt) return;                     // wave-uniform
    const int r0 = t * TROWS;

    f32x4 c0 = {0.f, 0.f, 0.f, 0.f}, c1 = c0, c2 = c0, c3 = c0;

    for (int it = 0; it < 27; ++it) {
        int src;
        if (it < 26) {
            src = tab[((size_t)it * nt + t) * 16 + col];
        } else {
            const int r = r0 + col;          // center: identity map
            src = (r < N) ? r : -1;
        }
        if (__ballot(src >= 0) == 0ull) continue;

        bf16x8 a0 = {0,0,0,0,0,0,0,0}, a1 = a0;
        if (src >= 0) {
            const bf16x8* fp = (const bf16x8*)(fb + (size_t)src * 64 + grp * 8);
            a0 = fp[0];                      // cin grp*8 .. +8
            a1 = fp[4];                      // cin 32+grp*8 .. +8
        }

        const unsigned short* wk = wt + kk_of_item(it) * 4096;
#pragma unroll
        for (int ot = 0; ot < 4; ++ot) {
            const bf16x8* wp = (const bf16x8*)(wk + (ot * 16 + col) * 64);
            const bf16x8 b0 = wp[grp];
            const bf16x8 b1 = wp[4 + grp];
            f32x4& cc = (ot == 0) ? c0 : (ot == 1) ? c1 : (ot == 2) ? c2 : c3;
            cc = __builtin_amdgcn_mfma_f32_16x16x32_bf16(a0, b0, cc, 0, 0, 0);
            cc = __builtin_amdgcn_mfma_f32_16x16x32_bf16(a1, b1, cc, 0, 0, 0);
        }
    }

#pragma unroll
    for (int ot = 0; ot < 4; ++ot) {
        const f32x4 cv = (ot == 0) ? c0 : (ot == 1) ? c1 : (ot == 2) ? c2 : c3;
#pragma unroll
        for (int reg = 0; reg < 4; ++reg) {
            const int r = r0 + grp * 4 + reg;
            if (r < N) out[(size_t)r * 64 + ot * 16 + col] = cv[reg];
        }
    }
}

// ---------- fallback (fp32 + atomics, round-0) ----------------------------
template <int MODE>
__global__ __launch_bounds__(256) void spconv_fb(
    const float* __restrict__ feats, const float* __restrict__ W,
    const int* __restrict__ imap, const int* __restrict__ omap,
    float* __restrict__ out, int npairs)
{
    __shared__ float4 wt4[16 * 64];
    const int tid = threadIdx.x, koff = blockIdx.y;
    const float* Wk;
    const int* im = nullptr; const int* om = nullptr;
    if (MODE == 0) Wk = W + 13 * (CIN * COUT);
    else {
        const int kk = (koff < 13) ? koff : koff + 1;
        Wk = W + (size_t)kk * (CIN * COUT);
        im = imap + (size_t)koff * npairs; om = omap + (size_t)koff * npairs;
    }
    float* wts = (float*)wt4;
    for (int idx = tid; idx < CIN * COUT; idx += 256) {
        const int c = idx >> 6, o = idx & 63;
        wts[((c >> 2) * 64 + o) * 4 + (c & 3)] = Wk[idx];
    }
    __syncthreads();
    const int o = tid & 63, w = tid >> 6;
    const int base = blockIdx.x * 256 + w * 64;
    const float4* f4p = (const float4*)feats;
    for (int n = 0; n < 64; ++n) {
        const int p = base + n;
        if (p >= npairs) break;
        int i, j;
        if (MODE == 0) { i = p; j = p; }
        else { i = im[p]; if (i < 0) continue; j = om[p]; }
        i = __builtin_amdgcn_readfirstlane(i);
        float a = 0.f;
#pragma unroll
        for (int c4 = 0; c4 < 16; ++c4) {
            const float4 f = f4p[(size_t)i * 16 + c4];
            const float4 wv = wt4[c4 * 64 + o];
            a += f.x * wv.x + f.y * wv.y + f.z * wv.z + f.w * wv.w;
        }
        if (MODE == 0) out[(size_t)j * COUT + o] = a;
        else atomicAdd(&out[(size_t)j * COUT + o], a);
    }
}

extern "C" void kernel_launch(void* const* d_in, const int* in_sizes, int n_in,
                              void* d_out, int out_size, void* d_ws, size_t ws_size,
                              hipStream_t stream) {
    const float* feats = (const float*)d_in[0];
    const float* W     = (const float*)d_in[1];
    const int* imap    = (const int*)d_in[2];
    const int* omap    = (const int*)d_in[3];
    float* out         = (float*)d_out;

    const int N = in_sizes[0] / CIN;
    const int P = in_sizes[2] / NOFF;
    const int nt = (N + TROWS - 1) / TROWS;

    const size_t fb_bytes  = (size_t)N * 64 * sizeof(unsigned short);      // 25.6 MB
    const size_t wt_bytes  = 27 * 64 * 64 * sizeof(unsigned short);        // 216 KB
    const size_t tab_bytes = (size_t)NOFF * nt * TROWS * sizeof(int);      // 20.8 MB

    if (ws_size < fb_bytes + wt_bytes + tab_bytes) {
        dim3 blk(256);
        dim3 gc((N + 255) / 256, 1);
        spconv_fb<0><<<gc, blk, 0, stream>>>(feats, W, nullptr, nullptr, out, N);
        dim3 go((P + 255) / 256, NOFF);
        spconv_fb<1><<<go, blk, 0, stream>>>(feats, W, imap, omap, out, P);
        return;
    }

    unsigned short* fbp = (unsigned short*)d_ws;
    unsigned short* Wt  = (unsigned short*)((char*)d_ws + fb_bytes);
    int* tab            = (int*)((char*)d_ws + fb_bytes + wt_bytes);

    const int nf = N * 64;
    prep_feats<<<(nf / 8 + 255) / 256, 256, 0, stream>>>(feats, fbp, nf);
    prep_wt<<<27, 256, 0, stream>>>(W, Wt);
    const int n4 = NOFF * nt * TROWS / 4;
    prep_tab_init<<<(n4 + 255) / 256, 256, 0, stream>>>((int4*)tab, n4);
    prep_tab<<<dim3((P + 255) / 256, NOFF), 256, 0, stream>>>(imap, omap, P, nt, tab);

    spconv_v4<<<(nt + 3) / 4, 256, 0, stream>>>(fbp, Wt, tab, out, N, nt);
}

// Round 5
// 95.471 us; speedup vs baseline: 3.8212x; 3.8212x over previous
//
#include <hip/hip_runtime.h>

// Submanifold sparse 3D conv — v5: offset-synchronous, output-stationary in
// registers, software-pipelined.
//  - wave owns TR=32 output rows = 2 x 16-row MFMA subtiles sharing W frags
//  - per item: prefetch next W (global->reg), next gather, tab 2 ahead;
//    compute current from LDS (XOR-swizzled, conflict-free ds_read_b128);
//    ds_write staged W; raw s_barrier + lgkmcnt(0) only (no vmcnt drain ->
//    prefetches stay in flight across the barrier)
//  - W pre-swizzled in global (prepass) so staging is a LINEAR copy
//
// Map identity (verified R1-R3): out[imap[m,p]] += feats[omap[m,p]] @ kernel[26-kk(m)]
// tab[m][tile][row-in-tile] = src row (omap) or -1, built from sorted imap.

#define CIN 64
#define COUT 64
#define TR 32
#define NOFF 26

typedef short bf16x8 __attribute__((ext_vector_type(8)));
typedef unsigned short ushort8 __attribute__((ext_vector_type(8)));
typedef float f32x4 __attribute__((ext_vector_type(4)));

__device__ inline unsigned short bfbits(float f) {
    unsigned u = __builtin_bit_cast(unsigned, f);
    u += 0x7fffu + ((u >> 16) & 1u);          // RNE
    return (unsigned short)(u >> 16);
}

__device__ inline int kk_of_item(int i) {
    return (i == 26) ? 13 : 26 - (i < 13 ? i : i + 1);
}

// ---------- prepass 1: feats f32 -> bf16 ----------------------------------
__global__ __launch_bounds__(256) void prep_feats(const float* __restrict__ f,
                                                  unsigned short* __restrict__ fb,
                                                  int n) {
    const int i8 = (blockIdx.x * 256 + threadIdx.x) * 8;
    if (i8 >= n) return;
    const float4 v0 = *(const float4*)(f + i8);
    const float4 v1 = *(const float4*)(f + i8 + 4);
    union { unsigned short u[8]; bf16x8 v; } r;
    r.u[0] = bfbits(v0.x); r.u[1] = bfbits(v0.y);
    r.u[2] = bfbits(v0.z); r.u[3] = bfbits(v0.w);
    r.u[4] = bfbits(v1.x); r.u[5] = bfbits(v1.y);
    r.u[6] = bfbits(v1.z); r.u[7] = bfbits(v1.w);
    *(bf16x8*)(fb + i8) = r.v;
}

// ---------- prepass 2: W [27][c][o] f32 -> Wt [27][o][c] bf16, PRE-SWIZZLED
// 16B unit q (=c>>3) of row o stored at unit position q ^ (o&7).
__global__ __launch_bounds__(256) void prep_wt(const float* __restrict__ W,
                                               unsigned short* __restrict__ Wt) {
    const int k = blockIdx.x;
    for (int idx = threadIdx.x; idx < CIN * COUT; idx += 256) {
        const int c = idx >> 6, o = idx & 63;
        const int q = c >> 3, e = c & 7;
        Wt[((k * 64 + o) * 64) + (((q ^ (o & 7)) << 3) + e)] =
            bfbits(W[(k * 64 + c) * 64 + o]);
    }
}

// ---------- prepass 3: column table init (-1) + scatter -------------------
__global__ __launch_bounds__(256) void prep_tab_init(int4* __restrict__ tab4, int n4) {
    const int i = blockIdx.x * 256 + threadIdx.x;
    if (i < n4) tab4[i] = make_int4(-1, -1, -1, -1);
}

__global__ __launch_bounds__(256) void prep_tab(const int* __restrict__ imap,
                                                const int* __restrict__ omap,
                                                int P, int nt,
                                                int* __restrict__ tab) {
    const int p = blockIdx.x * 256 + threadIdx.x;
    const int m = blockIdx.y;
    if (p >= P) return;
    const int iv = imap[(size_t)m * P + p];
    if (iv < 0) return;
    tab[((size_t)m * nt + (iv >> 5)) * TR + (iv & 31)] = omap[(size_t)m * P + p];
}

// ---------- main ----------------------------------------------------------
__global__ __launch_bounds__(256) void spconv_v5(
    const unsigned short* __restrict__ fb,   // feats bf16 [N][64]
    const unsigned short* __restrict__ wt,   // [27][64][64] bf16, pre-swizzled
    const int* __restrict__ tab,             // [26][nt][32]
    float* __restrict__ out, int N, int nt)
{
    __shared__ unsigned short wbuf[2][4096]; // 2 x 8KB double buffer

    const int tid = threadIdx.x, w = tid >> 6, lane = tid & 63;
    const int col = lane & 15, grp = lane >> 4;
    const int t = blockIdx.x * 4 + w;
    const bool vt = (t < nt);
    const int tt = vt ? t : (nt - 1);
    const int r0 = t * TR;

    // --- helpers (straight-line friendly) ---
    auto tabload = [&](int j) -> int {       // raw tab dword for item j (clamped)
        const int jc = (j < 26) ? j : 25;
        return 0;                            // placeholder (never used; see below)
    };
    (void)tabload;

#define TABLOAD(j, s) tab[((size_t)((j) < 26 ? (j) : 25) * nt + tt) * TR + (s) * 16 + col]
    // resolve src for item j, subtile s, given raw tab value tv
#define RESOLVE(j, s, tv) \
    ((!vt || (j) > 26) ? -1 : ((j) == 26 ? ((r0 + (s)*16 + col < N) ? r0 + (s)*16 + col : -1) : (tv)))

    // --- prologue ---
    int sv_c[2], sv_n[2], tv2[2], tv3[2];
#pragma unroll
    for (int s = 0; s < 2; ++s) {
        sv_c[s] = RESOLVE(0, s, TABLOAD(0, s));
        sv_n[s] = RESOLVE(1, s, TABLOAD(1, s));
        tv2[s] = TABLOAD(2, s);
        tv3[s] = TABLOAD(3, s);
    }

    bf16x8 a_cur[2][2], a_nx[2][2];
#pragma unroll
    for (int s = 0; s < 2; ++s) {
        const int sc = (sv_c[s] < 0) ? 0 : sv_c[s];
        const bf16x8* fp = (const bf16x8*)(fb + (size_t)sc * 64 + grp * 8);
        a_cur[s][0] = fp[0];
        a_cur[s][1] = fp[4];
    }

    // stage W(item 0): linear copy (source pre-swizzled)
    {
        const unsigned short* wk = wt + kk_of_item(0) * 4096;
        const ushort8 wl0 = *(const ushort8*)(wk + tid * 8);
        const ushort8 wl1 = *(const ushort8*)(wk + 2048 + tid * 8);
        *(ushort8*)(&wbuf[0][tid * 8]) = wl0;
        *(ushort8*)(&wbuf[0][2048 + tid * 8]) = wl1;
    }
    asm volatile("s_waitcnt lgkmcnt(0)" ::: "memory");
    __builtin_amdgcn_s_barrier();

    f32x4 acc[2][4];
#pragma unroll
    for (int s = 0; s < 2; ++s)
#pragma unroll
        for (int ot = 0; ot < 4; ++ot) acc[s][ot] = {0.f, 0.f, 0.f, 0.f};

    for (int it = 0; it < 27; ++it) {
        // (1) next item's W -> regs (global, L2-hot)
        const int itn = (it < 26) ? it + 1 : 26;
        const unsigned short* wkn = wt + kk_of_item(itn) * 4096;
        const ushort8 wl0 = *(const ushort8*)(wkn + tid * 8);
        const ushort8 wl1 = *(const ushort8*)(wkn + 2048 + tid * 8);

        // (2) next item's gather (clamped; masked next iteration)
#pragma unroll
        for (int s = 0; s < 2; ++s) {
            const int sc = (sv_n[s] < 0) ? 0 : sv_n[s];
            const bf16x8* fp = (const bf16x8*)(fb + (size_t)sc * 64 + grp * 8);
            a_nx[s][0] = fp[0];
            a_nx[s][1] = fp[4];
        }

        // (3) tab pipeline: resolve it+2, issue it+4
        int sv_nn[2];
#pragma unroll
        for (int s = 0; s < 2; ++s) {
            sv_nn[s] = RESOLVE(it + 2, s, tv2[s]);
            tv2[s] = tv3[s];
            tv3[s] = TABLOAD(it + 4, s);
        }

        // (4) mask current A by sv_c
#pragma unroll
        for (int s = 0; s < 2; ++s)
            if (sv_c[s] < 0) { a_cur[s][0] = (bf16x8)0; a_cur[s][1] = (bf16x8)0; }

        // (5) compute: 8 ds_read_b128 (swizzled, conflict-free) + 16 MFMA
        const unsigned short* cb = wbuf[it & 1];
#pragma unroll
        for (int ot = 0; ot < 4; ++ot) {
            const int o = ot * 16 + col;
            const bf16x8 b0 = *(const bf16x8*)(cb + o * 64 + ((grp ^ (col & 7)) << 3));
            const bf16x8 b1 = *(const bf16x8*)(cb + o * 64 + (((4 + grp) ^ (col & 7)) << 3));
#pragma unroll
            for (int s = 0; s < 2; ++s) {
                acc[s][ot] = __builtin_amdgcn_mfma_f32_16x16x32_bf16(a_cur[s][0], b0, acc[s][ot], 0, 0, 0);
                acc[s][ot] = __builtin_amdgcn_mfma_f32_16x16x32_bf16(a_cur[s][1], b1, acc[s][ot], 0, 0, 0);
            }
        }

        // (6) stage next W into the other buffer
        unsigned short* nb = wbuf[(it + 1) & 1];
        *(ushort8*)(&nb[tid * 8]) = wl0;
        *(ushort8*)(&nb[2048 + tid * 8]) = wl1;

        // (7) raw barrier: drain LDS ops only; vmem prefetches stay in flight
        asm volatile("s_waitcnt lgkmcnt(0)" ::: "memory");
        __builtin_amdgcn_s_barrier();

        // rotate
#pragma unroll
        for (int s = 0; s < 2; ++s) {
            sv_c[s] = sv_n[s];
            sv_n[s] = sv_nn[s];
            a_cur[s][0] = a_nx[s][0];
            a_cur[s][1] = a_nx[s][1];
        }
    }

    // --- write-out (one plain store per element) ---
    if (vt) {
#pragma unroll
        for (int s = 0; s < 2; ++s)
#pragma unroll
            for (int ot = 0; ot < 4; ++ot) {
                const f32x4 cv = acc[s][ot];
#pragma unroll
                for (int reg = 0; reg < 4; ++reg) {
                    const int r = r0 + s * 16 + grp * 4 + reg;
                    if (r < N) out[(size_t)r * 64 + ot * 16 + col] = cv[reg];
                }
            }
    }
#undef TABLOAD
#undef RESOLVE
}

// ---------- fallback (fp32 + atomics, round-0) ----------------------------
template <int MODE>
__global__ __launch_bounds__(256) void spconv_fb(
    const float* __restrict__ feats, const float* __restrict__ W,
    const int* __restrict__ imap, const int* __restrict__ omap,
    float* __restrict__ out, int npairs)
{
    __shared__ float4 wt4[16 * 64];
    const int tid = threadIdx.x, koff = blockIdx.y;
    const float* Wk;
    const int* im = nullptr; const int* om = nullptr;
    if (MODE == 0) Wk = W + 13 * (CIN * COUT);
    else {
        const int kk = (koff < 13) ? koff : koff + 1;
        Wk = W + (size_t)kk * (CIN * COUT);
        im = imap + (size_t)koff * npairs; om = omap + (size_t)koff * npairs;
    }
    float* wts = (float*)wt4;
    for (int idx = tid; idx < CIN * COUT; idx += 256) {
        const int c = idx >> 6, o = idx & 63;
        wts[((c >> 2) * 64 + o) * 4 + (c & 3)] = Wk[idx];
    }
    __syncthreads();
    const int o = tid & 63, w = tid >> 6;
    const int base = blockIdx.x * 256 + w * 64;
    const float4* f4p = (const float4*)feats;
    for (int n = 0; n < 64; ++n) {
        const int p = base + n;
        if (p >= npairs) break;
        int i, j;
        if (MODE == 0) { i = p; j = p; }
        else { i = im[p]; if (i < 0) continue; j = om[p]; }
        i = __builtin_amdgcn_readfirstlane(i);
        float a = 0.f;
#pragma unroll
        for (int c4 = 0; c4 < 16; ++c4) {
            const float4 f = f4p[(size_t)i * 16 + c4];
            const float4 wv = wt4[c4 * 64 + o];
            a += f.x * wv.x + f.y * wv.y + f.z * wv.z + f.w * wv.w;
        }
        if (MODE == 0) out[(size_t)j * COUT + o] = a;
        else atomicAdd(&out[(size_t)j * COUT + o], a);
    }
}

extern "C" void kernel_launch(void* const* d_in, const int* in_sizes, int n_in,
                              void* d_out, int out_size, void* d_ws, size_t ws_size,
                              hipStream_t stream) {
    const float* feats = (const float*)d_in[0];
    const float* W     = (const float*)d_in[1];
    const int* imap    = (const int*)d_in[2];
    const int* omap    = (const int*)d_in[3];
    float* out         = (float*)d_out;

    const int N = in_sizes[0] / CIN;
    const int P = in_sizes[2] / NOFF;
    const int nt = (N + TR - 1) / TR;                       // 32-row tiles (6250)

    const size_t fb_bytes  = (size_t)N * 64 * sizeof(unsigned short);   // 25.6 MB
    const size_t wt_bytes  = 27 * 64 * 64 * sizeof(unsigned short);     // 216 KB
    const size_t tab_bytes = (size_t)NOFF * nt * TR * sizeof(int);      // 20.8 MB

    if (ws_size < fb_bytes + wt_bytes + tab_bytes) {
        dim3 blk(256);
        dim3 gc((N + 255) / 256, 1);
        spconv_fb<0><<<gc, blk, 0, stream>>>(feats, W, nullptr, nullptr, out, N);
        dim3 go((P + 255) / 256, NOFF);
        spconv_fb<1><<<go, blk, 0, stream>>>(feats, W, imap, omap, out, P);
        return;
    }

    unsigned short* fbp = (unsigned short*)d_ws;
    unsigned short* Wt  = (unsigned short*)((char*)d_ws + fb_bytes);
    int* tab            = (int*)((char*)d_ws + fb_bytes + wt_bytes);

    const int nf = N * 64;
    prep_feats<<<(nf / 8 + 255) / 256, 256, 0, stream>>>(feats, fbp, nf);
    prep_wt<<<27, 256, 0, stream>>>(W, Wt);
    const int n4 = (int)(tab_bytes / 16);
    prep_tab_init<<<(n4 + 255) / 256, 256, 0, stream>>>((int4*)tab, n4);
    prep_tab<<<dim3((P + 255) / 256, NOFF), 256, 0, stream>>>(imap, omap, P, nt, tab);

    spconv_v5<<<(nt + 3) / 4, 256, 0, stream>>>(fbp, Wt, tab, out, N, nt);
}